// Round 12
// baseline (162.881 us; speedup 1.0000x reference)
//
#include <hip/hip_runtime.h>
#include <cstdint>
#include <cstddef>

#define TSEQ 512
#define DRNN 64
#define DIN  16

typedef float    f32x4 __attribute__((ext_vector_type(4)));
typedef unsigned u32x4 __attribute__((ext_vector_type(4)));
typedef _Float16 f16x8 __attribute__((ext_vector_type(8)));

#define MFMA16(A, B, C) __builtin_amdgcn_mfma_f32_16x16x32_f16((A), (B), (C), 0, 0, 0)

// pack two f32 -> f16x2 dword (v_cvt_pkrtz_f16_f32)
__device__ __forceinline__ unsigned packh(float a, float b) {
    return __builtin_bit_cast(unsigned, __builtin_amdgcn_cvt_pkrtz(a, b));
}
__device__ __forceinline__ f16x8 mkf(unsigned w0, unsigned w1, unsigned w2, unsigned w3) {
    u32x4 u = {w0, w1, w2, w3};
    return __builtin_bit_cast(f16x8, u);
}
__device__ __forceinline__ float tanh_fast(float x) {
    float e = __builtin_amdgcn_exp2f(x * 2.885390082f);
    float r = __builtin_amdgcn_rcpf(1.0f + e);
    return __builtin_fmaf(-2.0f, r, 1.0f);
}
// tanh of pre-scaled argument d = 2*log2(e)*z (scale folded into weights/bias)
__device__ __forceinline__ float tanh_pre(float d) {
    float e = __builtin_amdgcn_exp2f(d);
    float r = __builtin_amdgcn_rcpf(1.0f + e);
    return __builtin_fmaf(-2.0f, r, 1.0f);
}

// One fully-redundant step at time T (compile-time ring slot I=(T+1)&7).
// Self-feeding fragments: Bh0/Bh1 produced here ARE next step's B operands.
// FS: compile-time feat slot (-1 none, 0..2 = steps 509/510/511).
#define STEPA(I, FS, T, CLAMP) do {                                           \
    /* x-projection for step T+1 (independent of h chain) */                  \
    f32x4 xv_ = xreg[I];                                                      \
    f16x8 Bx_ = mkf(packh(xv_[0], xv_[1]), packh(xv_[2], xv_[3]), 0u, 0u);    \
    f32x4 xn0_ = MFMA16(WxF0, Bx_, bfr0);                                     \
    f32x4 xn1_ = MFMA16(WxF1, Bx_, bfr1);                                     \
    f32x4 xn2_ = MFMA16(WxF2, Bx_, bfr2);                                     \
    f32x4 xn3_ = MFMA16(WxF3, Bx_, bfr3);                                     \
    { int tl_ = (T) + 9;                                                      \
      if (CLAMP) { if (tl_ > TSEQ - 1) tl_ = TSEQ - 1; }                      \
      xreg[I] = *(const f32x4*)(xrow + (size_t)tl_ * DIN); }                  \
    /* h update: 4 tiles x 2 K-chunks */                                      \
    f32x4 d0_ = MFMA16(WhB0, Bh1, MFMA16(WhA0, Bh0, xc0));                    \
    f32x4 d1_ = MFMA16(WhB1, Bh1, MFMA16(WhA1, Bh0, xc1));                    \
    f32x4 d2_ = MFMA16(WhB2, Bh1, MFMA16(WhA2, Bh0, xc2));                    \
    f32x4 d3_ = MFMA16(WhB3, Bh1, MFMA16(WhA3, Bh0, xc3));                    \
    float v00_ = tanh_pre(d0_[0]), v01_ = tanh_pre(d0_[1]);                   \
    float v02_ = tanh_pre(d0_[2]), v03_ = tanh_pre(d0_[3]);                   \
    float v10_ = tanh_pre(d1_[0]), v11_ = tanh_pre(d1_[1]);                   \
    float v12_ = tanh_pre(d1_[2]), v13_ = tanh_pre(d1_[3]);                   \
    Bh0 = mkf(packh(v00_, v01_), packh(v02_, v03_),                           \
              packh(v10_, v11_), packh(v12_, v13_));                          \
    float v20_ = tanh_pre(d2_[0]), v21_ = tanh_pre(d2_[1]);                   \
    float v22_ = tanh_pre(d2_[2]), v23_ = tanh_pre(d2_[3]);                   \
    float v30_ = tanh_pre(d3_[0]), v31_ = tanh_pre(d3_[1]);                   \
    float v32_ = tanh_pre(d3_[2]), v33_ = tanh_pre(d3_[3]);                   \
    Bh1 = mkf(packh(v20_, v21_), packh(v22_, v23_),                           \
              packh(v30_, v31_), packh(v32_, v33_));                          \
    if ((FS) >= 0) {                                                          \
        float f00_ = tanh_fast(v00_), f01_ = tanh_fast(v01_);                 \
        float f02_ = tanh_fast(v02_), f03_ = tanh_fast(v03_);                 \
        float f10_ = tanh_fast(v10_), f11_ = tanh_fast(v11_);                 \
        float f12_ = tanh_fast(v12_), f13_ = tanh_fast(v13_);                 \
        float f20_ = tanh_fast(v20_), f21_ = tanh_fast(v21_);                 \
        float f22_ = tanh_fast(v22_), f23_ = tanh_fast(v23_);                 \
        float f30_ = tanh_fast(v30_), f31_ = tanh_fast(v31_);                 \
        float f32_ = tanh_fast(v32_), f33_ = tanh_fast(v33_);                 \
        featF[(FS) >= 0 ? 2 * (FS) : 0] =                                     \
            mkf(packh(f00_, f01_), packh(f02_, f03_),                         \
                packh(f10_, f11_), packh(f12_, f13_));                        \
        featF[(FS) >= 0 ? 2 * (FS) + 1 : 0] =                                 \
            mkf(packh(f20_, f21_), packh(f22_, f23_),                         \
                packh(f30_, f31_), packh(f32_, f33_));                        \
    }                                                                         \
    xc0 = xn0_; xc1 = xn1_; xc2 = xn2_; xc3 = xn3_;                           \
} while (0)

__global__ __launch_bounds__(64, 1) void rnn_nb(
    const float* __restrict__ X,
    const float* __restrict__ Wx,
    const float* __restrict__ Wh,
    const float* __restrict__ bias,
    const float* __restrict__ W1,
    const float* __restrict__ b1,
    const float* __restrict__ W2,
    const float* __restrict__ b2,
    float* __restrict__ out)
{
    const int lane = threadIdx.x & 63;
    const int li   = lane & 15;      // batch row (B/D col); weight M row for A
    const int g    = lane >> 4;      // k-slot group
    const int b0   = blockIdx.x * 16;
    const float S  = 2.885390082f;   // 2*log2(e), folded into Wh/Wx/bias

    // ---- persistent A fragments: full Wh^T (4 tiles x 2 K-chunks), f16 ----
    // slot map: k(c,g,e) = c*32 + (e<4 ? 4g+e : 16+4g+(e-4)); value S*Wh[k][16mt+li]
    auto loadWh = [&](int c, int mt) -> f16x8 {
        float wv[8];
        #pragma unroll
        for (int e = 0; e < 8; ++e) {
            int k = c * 32 + (e < 4 ? 4 * g + e : 16 + 4 * g + (e - 4));
            wv[e] = S * Wh[k * DRNN + 16 * mt + li];
        }
        return mkf(packh(wv[0], wv[1]), packh(wv[2], wv[3]),
                   packh(wv[4], wv[5]), packh(wv[6], wv[7]));
    };
    f16x8 WhA0 = loadWh(0, 0), WhA1 = loadWh(0, 1),
          WhA2 = loadWh(0, 2), WhA3 = loadWh(0, 3);
    f16x8 WhB0 = loadWh(1, 0), WhB1 = loadWh(1, 1),
          WhB2 = loadWh(1, 2), WhB3 = loadWh(1, 3);

    auto loadWx = [&](int mt) -> f16x8 {
        float wv[4];
        #pragma unroll
        for (int e = 0; e < 4; ++e)
            wv[e] = S * Wx[(4 * g + e) * DRNN + 16 * mt + li];
        return mkf(packh(wv[0], wv[1]), packh(wv[2], wv[3]), 0u, 0u);
    };
    f16x8 WxF0 = loadWx(0), WxF1 = loadWx(1), WxF2 = loadWx(2), WxF3 = loadWx(3);

    // scaled bias fragments (D rows 16mt+4g+q)
    f32x4 bfr0 = *(const f32x4*)(bias + 0 + 4 * g) * S;
    f32x4 bfr1 = *(const f32x4*)(bias + 16 + 4 * g) * S;
    f32x4 bfr2 = *(const f32x4*)(bias + 32 + 4 * g) * S;
    f32x4 bfr3 = *(const f32x4*)(bias + 48 + 4 * g) * S;

    // x ring: lane (li,g) owns X[b0+li][t][4g..4g+3]; slot I holds x_{t+1} at step t
    const float* xrow = X + (size_t)(b0 + li) * TSEQ * DIN + 4 * g;
    f32x4 xreg[8];
    #pragma unroll
    for (int i = 1; i < 8; ++i)
        xreg[i] = *(const f32x4*)(xrow + (size_t)i * DIN);
    xreg[0] = *(const f32x4*)(xrow + (size_t)8 * DIN);

    // prologue: xc = S*(bias + x_0 @ Wx)
    f32x4 xc0, xc1, xc2, xc3;
    {
        f32x4 x0v = *(const f32x4*)(xrow);
        f16x8 Bx0 = mkf(packh(x0v[0], x0v[1]), packh(x0v[2], x0v[3]), 0u, 0u);
        xc0 = MFMA16(WxF0, Bx0, bfr0);
        xc1 = MFMA16(WxF1, Bx0, bfr1);
        xc2 = MFMA16(WxF2, Bx0, bfr2);
        xc3 = MFMA16(WxF3, Bx0, bfr3);
    }
    // h_{-1} = 0 and feat frags
    f16x8 Bh0 = mkf(0u, 0u, 0u, 0u), Bh1 = mkf(0u, 0u, 0u, 0u);
    f16x8 featF[6];
    #pragma unroll
    for (int i = 0; i < 6; ++i) featF[i] = mkf(0u, 0u, 0u, 0u);

    // main loop: steps 0..495 (62 x 8), ring slots static, no clamp (t+9 <= 504)
    for (int tb = 0; tb < TSEQ - 16; tb += 8) {
        STEPA(1, -1, tb + 0, 0);
        STEPA(2, -1, tb + 1, 0);
        STEPA(3, -1, tb + 2, 0);
        STEPA(4, -1, tb + 3, 0);
        STEPA(5, -1, tb + 4, 0);
        STEPA(6, -1, tb + 5, 0);
        STEPA(7, -1, tb + 6, 0);
        STEPA(0, -1, tb + 7, 0);
    }
    // peeled: steps 496..511, clamped reloads, feat at 509/510/511
    STEPA(1, -1, 496, 1);
    STEPA(2, -1, 497, 1);
    STEPA(3, -1, 498, 1);
    STEPA(4, -1, 499, 1);
    STEPA(5, -1, 500, 1);
    STEPA(6, -1, 501, 1);
    STEPA(7, -1, 502, 1);
    STEPA(0, -1, 503, 1);
    STEPA(1, -1, 504, 1);
    STEPA(2, -1, 505, 1);
    STEPA(3, -1, 506, 1);
    STEPA(4, -1, 507, 1);
    STEPA(5, -1, 508, 1);
    STEPA(6,  0, 509, 1);
    STEPA(7,  1, 510, 1);
    STEPA(0,  2, 511, 1);

    // ---- MLP epilogue, all-register MFMA: out = tanh(feat@W1+b1)@W2 + b2 ----
    // featF[c6] packing matches B slot map for K-chunk c6 = 2s + (mt>>1).
    float p = 0.f;
    #pragma unroll
    for (int nt = 0; nt < 8; ++nt) {
        f32x4 a = *(const f32x4*)(b1 + nt * 16 + 4 * g);
        #pragma unroll
        for (int c6 = 0; c6 < 6; ++c6) {
            float wv[8];
            #pragma unroll
            for (int e = 0; e < 8; ++e) {
                int k = c6 * 32 + (e < 4 ? 4 * g + e : 16 + 4 * g + (e - 4));
                wv[e] = W1[k * 128 + nt * 16 + li];
            }
            f16x8 wf = mkf(packh(wv[0], wv[1]), packh(wv[2], wv[3]),
                           packh(wv[4], wv[5]), packh(wv[6], wv[7]));
            a = MFMA16(wf, featF[c6], a);
        }
        f32x4 w2v = *(const f32x4*)(W2 + nt * 16 + 4 * g);
        p += tanh_fast(a[0]) * w2v[0] + tanh_fast(a[1]) * w2v[1]
           + tanh_fast(a[2]) * w2v[2] + tanh_fast(a[3]) * w2v[3];
    }
    p += __shfl_xor(p, 16);
    p += __shfl_xor(p, 32);
    if (lane < 16) out[b0 + lane] = p + b2[0];
}

extern "C" void kernel_launch(void* const* d_in, const int* in_sizes, int n_in,
                              void* d_out, int out_size, void* d_ws, size_t ws_size,
                              hipStream_t stream) {
    const float* X    = (const float*)d_in[0];
    const float* Wx   = (const float*)d_in[1];
    const float* Wh   = (const float*)d_in[2];
    const float* bias = (const float*)d_in[3];
    const float* W1   = (const float*)d_in[4];
    const float* b1   = (const float*)d_in[5];
    const float* W2   = (const float*)d_in[6];
    const float* b2   = (const float*)d_in[7];
    rnn_nb<<<256, 64, 0, stream>>>(X, Wx, Wh, bias, W1, b1, W2, b2, (float*)d_out);
}